// Round 1
// baseline (275.449 us; speedup 1.0000x reference)
//
#include <hip/hip_runtime.h>
#include <hip/hip_bf16.h>
#include <cstdint>
#include <cstddef>

#define BD 2
#define SEQ 2048
#define NH 16
#define HD 64
#define IND 1024
#define QKVD 3072
#define MROWS (BD * SEQ) /* 4096 */

typedef __attribute__((ext_vector_type(8))) short s8v;
typedef __attribute__((ext_vector_type(4))) short s4v;
typedef __attribute__((ext_vector_type(4))) float f4v;

__device__ __forceinline__ short f2bf(float f) {
  __hip_bfloat16 h = __float2bfloat16(f);
  return *reinterpret_cast<short*>(&h);
}

__device__ __forceinline__ void async_copy16(void* lds, const void* g) {
  __builtin_amdgcn_global_load_lds(
      (const __attribute__((address_space(1))) unsigned int*)g,
      (__attribute__((address_space(3))) unsigned int*)lds, 16, 0, 0);
}

// ---------------- prep kernels ----------------
__global__ void k_cast(const float* __restrict__ in, short* __restrict__ out, int n4) {
  int i = blockIdx.x * blockDim.x + threadIdx.x;
  if (i >= n4) return;
  float4 v = reinterpret_cast<const float4*>(in)[i];
  s4v o;
  o[0] = f2bf(v.x); o[1] = f2bf(v.y); o[2] = f2bf(v.z); o[3] = f2bf(v.w);
  reinterpret_cast<s4v*>(out)[i] = o;
}

// w: [R][C] f32 row-major  ->  wT: [C][R] bf16 row-major
__global__ void k_transpose_cast(const float* __restrict__ w, short* __restrict__ wT,
                                 int R, int C) {
  __shared__ float tile[32][33];
  int c0 = blockIdx.x * 32, r0 = blockIdx.y * 32;
  int tx = threadIdx.x, ty = threadIdx.y; // (32,8)
  #pragma unroll
  for (int j = 0; j < 32; j += 8)
    tile[ty + j][tx] = w[(size_t)(r0 + ty + j) * C + c0 + tx];
  __syncthreads();
  #pragma unroll
  for (int j = 0; j < 32; j += 8)
    wT[(size_t)(c0 + ty + j) * R + r0 + tx] = f2bf(tile[tx][ty + j]);
}

// ---------------- GEMM: C = A[M][K] * BT[N][K]^T + bias ----------------
// MODE 0: scatter bf16 into Q/K/V (B,H,N,D), Q pre-scaled by 0.125
// MODE 1: fp32 out row-major
template <int MODE>
__global__ __launch_bounds__(256) void k_gemm(const short* __restrict__ A,
                                              const short* __restrict__ BT,
                                              const float* __restrict__ bias,
                                              short* __restrict__ obf,
                                              float* __restrict__ ofl,
                                              int Mr, int Nc, int K) {
  constexpr int BM = 128, BN = 128, BK = 32;
  __shared__ short As[BM][BK];
  __shared__ short Bs[BN][BK];
  const int rm = blockIdx.x * BM, cn = blockIdx.y * BN;
  const int t = threadIdx.x, l = t & 63;
  const int wm = (t >> 6) >> 1, wn = (t >> 6) & 1;
  const int lr = l & 15, lc = l >> 4;

  f4v acc[4][4];
  #pragma unroll
  for (int m = 0; m < 4; ++m)
    #pragma unroll
    for (int n = 0; n < 4; ++n) acc[m][n] = (f4v)0.0f;

  for (int k0 = 0; k0 < K; k0 += BK) {
    __syncthreads();
    #pragma unroll
    for (int p = 0; p < 2; ++p) {
      int c = p * 256 + t; // 16B chunk id; LDS offset = c*16 (linear, wave-uniform+lane*16)
      async_copy16(&As[c >> 2][(c & 3) * 8],
                   &A[(size_t)(rm + (c >> 2)) * K + k0 + (c & 3) * 8]);
      async_copy16(&Bs[c >> 2][(c & 3) * 8],
                   &BT[(size_t)(cn + (c >> 2)) * K + k0 + (c & 3) * 8]);
    }
    __syncthreads();
    s8v af[4], bf[4];
    #pragma unroll
    for (int m = 0; m < 4; ++m)
      af[m] = *(const s8v*)&As[wm * 64 + m * 16 + lr][lc * 8];
    #pragma unroll
    for (int n = 0; n < 4; ++n)
      bf[n] = *(const s8v*)&Bs[wn * 64 + n * 16 + lr][lc * 8];
    #pragma unroll
    for (int m = 0; m < 4; ++m)
      #pragma unroll
      for (int n = 0; n < 4; ++n)
        acc[m][n] = __builtin_amdgcn_mfma_f32_16x16x32_bf16(af[m], bf[n], acc[m][n], 0, 0, 0);
  }

  const int row0 = rm + wm * 64, col0 = cn + wn * 64;
  #pragma unroll
  for (int n = 0; n < 4; ++n) {
    const int col = col0 + n * 16 + lr;
    const float bv = bias[col];
    if (MODE == 0) {
      const int h = col / 192, rem = col % 192;
      const int wch = rem >> 6, d = rem & 63;
      const float scale = (wch == 0) ? 0.125f : 1.0f;
      short* dst = obf + (size_t)wch * ((size_t)BD * NH * SEQ * HD);
      #pragma unroll
      for (int m = 0; m < 4; ++m)
        #pragma unroll
        for (int r = 0; r < 4; ++r) {
          const int row = row0 + m * 16 + lc * 4 + r;
          const int b = row >> 11, nn = row & (SEQ - 1);
          dst[((size_t)(b * NH + h) * SEQ + nn) * HD + d] =
              f2bf((acc[m][n][r] + bv) * scale);
        }
    } else {
      #pragma unroll
      for (int m = 0; m < 4; ++m)
        #pragma unroll
        for (int r = 0; r < 4; ++r) {
          const int row = row0 + m * 16 + lc * 4 + r;
          ofl[(size_t)row * Nc + col] = acc[m][n][r] + bv;
        }
    }
  }
}

// ---------------- flash attention (Q pre-scaled) ----------------
// grid (SEQ/64, BD*NH), block 256. Each wave owns 16 q rows; KV tiles of 64.
__global__ __launch_bounds__(256) void k_attn(const short* __restrict__ Qw,
                                              const short* __restrict__ Kw,
                                              const short* __restrict__ Vw,
                                              short* __restrict__ AO) {
  const int qb = blockIdx.x, bh = blockIdx.y;
  const size_t base = (size_t)bh * SEQ * HD;
  const int t = threadIdx.x, l = t & 63, w = t >> 6;
  const int lr = l & 15, lc = l >> 4;
  __shared__ short Ks[64][64];
  __shared__ short Vt[64][64]; // V transposed: Vt[d][kv]
  __shared__ short Ps[4][16][64];
  const int q0 = qb * 64 + w * 16;

  s8v qf[2];
  #pragma unroll
  for (int s = 0; s < 2; ++s)
    qf[s] = *(const s8v*)&Qw[base + (size_t)(q0 + lr) * HD + s * 32 + lc * 8];

  f4v of[4];
  #pragma unroll
  for (int j = 0; j < 4; ++j) of[j] = (f4v)0.0f;
  float Mx = -3.0e38f, Ls = 0.0f;

  for (int kv = 0; kv < SEQ; kv += 64) {
    __syncthreads();
    #pragma unroll
    for (int p = 0; p < 2; ++p) { // K tile: linear global_load_lds
      int c = p * 256 + t;
      async_copy16(&Ks[c >> 3][(c & 7) * 8],
                   &Kw[base + (size_t)(kv + (c >> 3)) * HD + (c & 7) * 8]);
    }
    #pragma unroll
    for (int p = 0; p < 2; ++p) { // V tile: transpose via register staging
      int c = p * 256 + t;
      const int row = c >> 3, d0 = (c & 7) * 8;
      s8v vv = *(const s8v*)&Vw[base + (size_t)(kv + row) * HD + d0];
      #pragma unroll
      for (int i = 0; i < 8; ++i) Vt[d0 + i][row] = vv[i];
    }
    __syncthreads();

    // S^T = K * Q^T : lane holds S[q=lr][kv = j*16 + lc*4 + r]
    f4v st[4];
    #pragma unroll
    for (int j = 0; j < 4; ++j) st[j] = (f4v)0.0f;
    #pragma unroll
    for (int j = 0; j < 4; ++j)
      #pragma unroll
      for (int s = 0; s < 2; ++s) {
        s8v kf = *(const s8v*)&Ks[j * 16 + lr][s * 32 + lc * 8];
        st[j] = __builtin_amdgcn_mfma_f32_16x16x32_bf16(kf, qf[s], st[j], 0, 0, 0);
      }

    // online softmax per q-row (= lane lr, replicated over 4 groups)
    float pm = -3.0e38f;
    #pragma unroll
    for (int j = 0; j < 4; ++j)
      #pragma unroll
      for (int r = 0; r < 4; ++r) pm = fmaxf(pm, st[j][r]);
    pm = fmaxf(pm, __shfl_xor(pm, 16));
    pm = fmaxf(pm, __shfl_xor(pm, 32));
    const float Mn = fmaxf(Mx, pm);
    const float alpha = __expf(Mx - Mn);
    float rs = 0.0f;
    #pragma unroll
    for (int j = 0; j < 4; ++j) {
      s4v pk;
      #pragma unroll
      for (int r = 0; r < 4; ++r) {
        const float p = __expf(st[j][r] - Mn);
        rs += p;
        pk[r] = f2bf(p);
      }
      *(s4v*)&Ps[w][lr][j * 16 + lc * 4] = pk;
    }
    rs += __shfl_xor(rs, 16);
    rs += __shfl_xor(rs, 32);
    Ls = Ls * alpha + rs;
    Mx = Mn;

    // rescale O (O rows are q = lc*4 + r -> fetch alpha from lane q)
    float al[4];
    #pragma unroll
    for (int r = 0; r < 4; ++r) al[r] = __shfl(alpha, lc * 4 + r);
    #pragma unroll
    for (int jd = 0; jd < 4; ++jd)
      #pragma unroll
      for (int r = 0; r < 4; ++r) of[jd][r] *= al[r];

    asm volatile("s_waitcnt lgkmcnt(0)" ::: "memory"); // P writes visible wave-wide

    // O += P * V
    #pragma unroll
    for (int s = 0; s < 2; ++s) {
      s8v pf = *(const s8v*)&Ps[w][lr][s * 32 + lc * 8];
      #pragma unroll
      for (int jd = 0; jd < 4; ++jd) {
        s8v vf = *(const s8v*)&Vt[jd * 16 + lr][s * 32 + lc * 8];
        of[jd] = __builtin_amdgcn_mfma_f32_16x16x32_bf16(pf, vf, of[jd], 0, 0, 0);
      }
    }
  }

  float li[4];
  #pragma unroll
  for (int r = 0; r < 4; ++r) li[r] = 1.0f / __shfl(Ls, lc * 4 + r);
  const int b = bh >> 4, h = bh & 15;
  #pragma unroll
  for (int jd = 0; jd < 4; ++jd)
    #pragma unroll
    for (int r = 0; r < 4; ++r) {
      const int nq = q0 + lc * 4 + r;
      AO[(size_t)(b * SEQ + nq) * (NH * HD) + h * HD + jd * 16 + lr] =
          f2bf(of[jd][r] * li[r]);
    }
}

// ---------------- launch ----------------
extern "C" void kernel_launch(void* const* d_in, const int* in_sizes, int n_in,
                              void* d_out, int out_size, void* d_ws, size_t ws_size,
                              hipStream_t stream) {
  const float* x      = (const float*)d_in[0];
  const float* w_qkv  = (const float*)d_in[1];
  const float* b_qkv  = (const float*)d_in[2];
  const float* w_proj = (const float*)d_in[3];
  const float* b_proj = (const float*)d_in[4];
  float* out = (float*)d_out;

  char* ws = (char*)d_ws;
  short* xb  = (short*)(ws);                 //  8 MB  x as bf16 [4096][1024]
  short* wqT = (short*)(ws + 8388608);       //  6 MB  w_qkv^T bf16 [3072][1024]
  short* wpT = (short*)(ws + 14680064);      //  2 MB  w_proj^T bf16 [1024][1024]
  short* Qw  = (short*)(ws + 16777216);      //  8 MB  (B,H,N,D) bf16, pre-scaled
  short* Kw  = (short*)(ws + 25165824);      //  8 MB
  short* Vw  = (short*)(ws + 33554432);      //  8 MB
  short* AO  = (short*)(ws + 41943040);      //  8 MB  attn out (B,N,H*D) bf16

  k_cast<<<(MROWS * IND / 4 + 255) / 256, 256, 0, stream>>>(x, xb, MROWS * IND / 4);
  dim3 tb(32, 8);
  k_transpose_cast<<<dim3(QKVD / 32, IND / 32), tb, 0, stream>>>(w_qkv, wqT, IND, QKVD);
  k_transpose_cast<<<dim3(IND / 32, IND / 32), tb, 0, stream>>>(w_proj, wpT, IND, IND);

  k_gemm<0><<<dim3(MROWS / 128, QKVD / 128), 256, 0, stream>>>(
      xb, wqT, b_qkv, Qw, nullptr, MROWS, QKVD, IND);
  k_attn<<<dim3(SEQ / 64, BD * NH), 256, 0, stream>>>(Qw, Kw, Vw, AO);
  k_gemm<1><<<dim3(MROWS / 128, IND / 128), 256, 0, stream>>>(
      AO, wpT, b_proj, nullptr, out, MROWS, IND, IND);
}

// Round 2
// 154.856 us; speedup vs baseline: 1.7787x; 1.7787x over previous
//
#include <hip/hip_runtime.h>
#include <hip/hip_bf16.h>
#include <cstdint>
#include <cstddef>

#define BD 2
#define SEQ 2048
#define NH 16
#define HD 64
#define IND 1024
#define QKVD 3072
#define MROWS (BD * SEQ) /* 4096 */

typedef __attribute__((ext_vector_type(8))) short s8v;
typedef __attribute__((ext_vector_type(4))) short s4v;
typedef __attribute__((ext_vector_type(4))) float f4v;

__device__ __forceinline__ short f2bf(float f) {
  __hip_bfloat16 h = __float2bfloat16(f);
  return *reinterpret_cast<short*>(&h);
}

__device__ __forceinline__ void async_copy16(void* lds, const void* g) {
  __builtin_amdgcn_global_load_lds(
      (const __attribute__((address_space(1))) unsigned int*)g,
      (__attribute__((address_space(3))) unsigned int*)lds, 16, 0, 0);
}

// XOR-swizzled access into a [rows][64] bf16 LDS tile (128 B rows).
// byte ^= ((row&7)<<4) spreads the 16-lane column read across 8 bank-slots.
__device__ __forceinline__ const s8v* lds_frag(const short* p, int row, int col) {
  int byte = (row << 7) + (col << 1);
  byte ^= ((row & 7) << 4);
  return (const s8v*)((const char*)p + byte);
}

// ---------------- prep kernels ----------------
__global__ void k_cast(const float* __restrict__ in, short* __restrict__ out, int n4) {
  int i = blockIdx.x * blockDim.x + threadIdx.x;
  if (i >= n4) return;
  float4 v = reinterpret_cast<const float4*>(in)[i];
  s4v o;
  o[0] = f2bf(v.x); o[1] = f2bf(v.y); o[2] = f2bf(v.z); o[3] = f2bf(v.w);
  reinterpret_cast<s4v*>(out)[i] = o;
}

// w: [R][C] f32 row-major  ->  wT: [C][R] bf16 row-major
__global__ void k_transpose_cast(const float* __restrict__ w, short* __restrict__ wT,
                                 int R, int C) {
  __shared__ float tile[32][33];
  int c0 = blockIdx.x * 32, r0 = blockIdx.y * 32;
  int tx = threadIdx.x, ty = threadIdx.y; // (32,8)
  #pragma unroll
  for (int j = 0; j < 32; j += 8)
    tile[ty + j][tx] = w[(size_t)(r0 + ty + j) * C + c0 + tx];
  __syncthreads();
  #pragma unroll
  for (int j = 0; j < 32; j += 8)
    wT[(size_t)(c0 + ty + j) * R + r0 + tx] = f2bf(tile[tx][ty + j]);
}

// ---------------- GEMM: C = A[M][K] * BT[N][K]^T + bias ----------------
// MODE 0: scatter bf16 into Q/K (B,H,N,D) and V TRANSPOSED (B,H,D,N);
//         Q pre-scaled by 0.125
// MODE 1: fp32 out row-major
template <int MODE>
__global__ __launch_bounds__(256) void k_gemm(const short* __restrict__ A,
                                              const short* __restrict__ BT,
                                              const float* __restrict__ bias,
                                              short* __restrict__ obf,
                                              float* __restrict__ ofl,
                                              int Mr, int Nc, int K) {
  constexpr int BM = 128, BN = 128, BK = 32;
  __shared__ short As[BM][BK];
  __shared__ short Bs[BN][BK];
  const int rm = blockIdx.x * BM, cn = blockIdx.y * BN;
  const int t = threadIdx.x, l = t & 63;
  const int wm = (t >> 6) >> 1, wn = (t >> 6) & 1;
  const int lr = l & 15, lc = l >> 4;

  f4v acc[4][4];
  #pragma unroll
  for (int m = 0; m < 4; ++m)
    #pragma unroll
    for (int n = 0; n < 4; ++n) acc[m][n] = (f4v)0.0f;

  for (int k0 = 0; k0 < K; k0 += BK) {
    __syncthreads();
    #pragma unroll
    for (int p = 0; p < 2; ++p) {
      int c = p * 256 + t; // 16B chunk id; LDS offset = c*16 (linear)
      async_copy16(&As[c >> 2][(c & 3) * 8],
                   &A[(size_t)(rm + (c >> 2)) * K + k0 + (c & 3) * 8]);
      async_copy16(&Bs[c >> 2][(c & 3) * 8],
                   &BT[(size_t)(cn + (c >> 2)) * K + k0 + (c & 3) * 8]);
    }
    __syncthreads();
    s8v af[4], bf[4];
    #pragma unroll
    for (int m = 0; m < 4; ++m)
      af[m] = *(const s8v*)&As[wm * 64 + m * 16 + lr][lc * 8];
    #pragma unroll
    for (int n = 0; n < 4; ++n)
      bf[n] = *(const s8v*)&Bs[wn * 64 + n * 16 + lr][lc * 8];
    #pragma unroll
    for (int m = 0; m < 4; ++m)
      #pragma unroll
      for (int n = 0; n < 4; ++n)
        acc[m][n] = __builtin_amdgcn_mfma_f32_16x16x32_bf16(af[m], bf[n], acc[m][n], 0, 0, 0);
  }

  const int row0 = rm + wm * 64, col0 = cn + wn * 64;
  #pragma unroll
  for (int n = 0; n < 4; ++n) {
    const int col = col0 + n * 16 + lr;
    const float bv = bias[col];
    if (MODE == 0) {
      const int h = col / 192, rem = col % 192;
      const int wch = rem >> 6, d = rem & 63;
      const float scale = (wch == 0) ? 0.125f : 1.0f;
      short* dst = obf + (size_t)wch * ((size_t)BD * NH * SEQ * HD);
      #pragma unroll
      for (int m = 0; m < 4; ++m)
        #pragma unroll
        for (int r = 0; r < 4; ++r) {
          const int row = row0 + m * 16 + lc * 4 + r;
          const int b = row >> 11, nn = row & (SEQ - 1);
          const short val = f2bf((acc[m][n][r] + bv) * scale);
          if (wch == 2) // V stored transposed: [bh][d][n]
            dst[((size_t)(b * NH + h) * HD + d) * SEQ + nn] = val;
          else
            dst[((size_t)(b * NH + h) * SEQ + nn) * HD + d] = val;
        }
    } else {
      #pragma unroll
      for (int m = 0; m < 4; ++m)
        #pragma unroll
        for (int r = 0; r < 4; ++r) {
          const int row = row0 + m * 16 + lc * 4 + r;
          ofl[(size_t)row * Nc + col] = acc[m][n][r] + bv;
        }
    }
  }
}

// ---------------- flash attention (Q pre-scaled, V^T input) ----------------
// grid (SEQ/64, BD*NH), block 256. Each wave owns 16 q rows; KV tiles of 64.
// All LDS tiles XOR-swizzled (T2): linear global_load_lds dest + pre-swizzled
// global source chunk, swizzled ds_read (rule #21: both-sides-or-neither).
__global__ __launch_bounds__(256) void k_attn(const short* __restrict__ Qw,
                                              const short* __restrict__ Kw,
                                              const short* __restrict__ Vt_g,
                                              short* __restrict__ AO) {
  const int qb = blockIdx.x, bh = blockIdx.y;
  const size_t base = (size_t)bh * SEQ * HD;
  const int t = threadIdx.x, l = t & 63, w = t >> 6;
  const int lr = l & 15, lc = l >> 4;
  __shared__ short Ks[64 * 64];
  __shared__ short Vt[64 * 64];      // V^T tile: [d][kv]
  __shared__ short Ps[4][16 * 64];   // per-wave P, swizzled
  const int q0 = qb * 64 + w * 16;

  s8v qf[2];
  #pragma unroll
  for (int s = 0; s < 2; ++s)
    qf[s] = *(const s8v*)&Qw[base + (size_t)(q0 + lr) * HD + s * 32 + lc * 8];

  f4v of[4];
  #pragma unroll
  for (int j = 0; j < 4; ++j) of[j] = (f4v)0.0f;
  float Mx = -3.0e38f, Ls = 0.0f;
  short* Pw = &Ps[w][0];

  for (int kv = 0; kv < SEQ; kv += 64) {
    __syncthreads();
    #pragma unroll
    for (int p = 0; p < 2; ++p) { // K tile, source chunk pre-swizzled
      int c = p * 256 + t;
      int row = c >> 3, ch = (c & 7) ^ (row & 7);
      async_copy16((char*)Ks + c * 16,
                   &Kw[base + (size_t)(kv + row) * HD + ch * 8]);
    }
    #pragma unroll
    for (int p = 0; p < 2; ++p) { // V^T tile: row d, cols kv..kv+63
      int c = p * 256 + t;
      int row = c >> 3, ch = (c & 7) ^ (row & 7);
      async_copy16((char*)Vt + c * 16,
                   &Vt_g[base + (size_t)row * SEQ + kv + ch * 8]);
    }
    __syncthreads();

    // S^T = K * Q^T : lane holds S[q=lr][kv = j*16 + lc*4 + r]
    f4v st[4];
    #pragma unroll
    for (int j = 0; j < 4; ++j) st[j] = (f4v)0.0f;
    #pragma unroll
    for (int j = 0; j < 4; ++j)
      #pragma unroll
      for (int s = 0; s < 2; ++s) {
        s8v kf = *lds_frag(Ks, j * 16 + lr, s * 32 + lc * 8);
        st[j] = __builtin_amdgcn_mfma_f32_16x16x32_bf16(kf, qf[s], st[j], 0, 0, 0);
      }

    // online softmax per q-row (= lane lr, replicated over 4 groups)
    float pm = -3.0e38f;
    #pragma unroll
    for (int j = 0; j < 4; ++j)
      #pragma unroll
      for (int r = 0; r < 4; ++r) pm = fmaxf(pm, st[j][r]);
    pm = fmaxf(pm, __shfl_xor(pm, 16));
    pm = fmaxf(pm, __shfl_xor(pm, 32));
    const float Mn = fmaxf(Mx, pm);
    const float alpha = __expf(Mx - Mn);
    float rs = 0.0f;
    #pragma unroll
    for (int j = 0; j < 4; ++j) {
      s4v pk;
      #pragma unroll
      for (int r = 0; r < 4; ++r) {
        const float p = __expf(st[j][r] - Mn);
        rs += p;
        pk[r] = f2bf(p);
      }
      int byte = (lr << 7) + ((j * 16 + lc * 4) << 1);
      byte ^= ((lr & 7) << 4);
      *(s4v*)((char*)Pw + byte) = pk;
    }
    rs += __shfl_xor(rs, 16);
    rs += __shfl_xor(rs, 32);
    Ls = Ls * alpha + rs;
    Mx = Mn;

    // rescale O (O rows are q = lc*4 + r -> fetch alpha from lane q)
    float al[4];
    #pragma unroll
    for (int r = 0; r < 4; ++r) al[r] = __shfl(alpha, lc * 4 + r);
    #pragma unroll
    for (int jd = 0; jd < 4; ++jd)
      #pragma unroll
      for (int r = 0; r < 4; ++r) of[jd][r] *= al[r];

    // O += P * V (P per-wave; intra-wave LDS ops complete in order)
    #pragma unroll
    for (int s = 0; s < 2; ++s) {
      s8v pf = *lds_frag(Pw, lr, s * 32 + lc * 8);
      #pragma unroll
      for (int jd = 0; jd < 4; ++jd) {
        s8v vf = *lds_frag(Vt, jd * 16 + lr, s * 32 + lc * 8);
        of[jd] = __builtin_amdgcn_mfma_f32_16x16x32_bf16(pf, vf, of[jd], 0, 0, 0);
      }
    }
  }

  float li[4];
  #pragma unroll
  for (int r = 0; r < 4; ++r) li[r] = 1.0f / __shfl(Ls, lc * 4 + r);
  const int b = bh >> 4, h = bh & 15;
  #pragma unroll
  for (int jd = 0; jd < 4; ++jd)
    #pragma unroll
    for (int r = 0; r < 4; ++r) {
      const int nq = q0 + lc * 4 + r;
      AO[(size_t)(b * SEQ + nq) * (NH * HD) + h * HD + jd * 16 + lr] =
          f2bf(of[jd][r] * li[r]);
    }
}

// ---------------- launch ----------------
extern "C" void kernel_launch(void* const* d_in, const int* in_sizes, int n_in,
                              void* d_out, int out_size, void* d_ws, size_t ws_size,
                              hipStream_t stream) {
  const float* x      = (const float*)d_in[0];
  const float* w_qkv  = (const float*)d_in[1];
  const float* b_qkv  = (const float*)d_in[2];
  const float* w_proj = (const float*)d_in[3];
  const float* b_proj = (const float*)d_in[4];
  float* out = (float*)d_out;

  char* ws = (char*)d_ws;
  short* xb  = (short*)(ws);                 //  8 MB  x as bf16 [4096][1024]
  short* wqT = (short*)(ws + 8388608);       //  6 MB  w_qkv^T bf16 [3072][1024]
  short* wpT = (short*)(ws + 14680064);      //  2 MB  w_proj^T bf16 [1024][1024]
  short* Qw  = (short*)(ws + 16777216);      //  8 MB  (B,H,N,D) bf16, pre-scaled
  short* Kw  = (short*)(ws + 25165824);      //  8 MB  (B,H,N,D)
  short* Vtg = (short*)(ws + 33554432);      //  8 MB  (B,H,D,N)  V transposed
  short* AO  = (short*)(ws + 41943040);      //  8 MB  attn out (B,N,H*D) bf16

  k_cast<<<(MROWS * IND / 4 + 255) / 256, 256, 0, stream>>>(x, xb, MROWS * IND / 4);
  dim3 tb(32, 8);
  k_transpose_cast<<<dim3(QKVD / 32, IND / 32), tb, 0, stream>>>(w_qkv, wqT, IND, QKVD);
  k_transpose_cast<<<dim3(IND / 32, IND / 32), tb, 0, stream>>>(w_proj, wpT, IND, IND);

  k_gemm<0><<<dim3(MROWS / 128, QKVD / 128), 256, 0, stream>>>(
      xb, wqT, b_qkv, Qw, nullptr, MROWS, QKVD, IND);
  k_attn<<<dim3(SEQ / 64, BD * NH), 256, 0, stream>>>(Qw, Kw, Vtg, AO);
  k_gemm<1><<<dim3(MROWS / 128, IND / 128), 256, 0, stream>>>(
      AO, wpT, b_proj, nullptr, out, MROWS, IND, IND);
}